// Round 1
// baseline (143.005 us; speedup 1.0000x reference)
//
#include <hip/hip_runtime.h>
#include <stdint.h>

constexpr int kB = 8, kH = 8, kS = 1024, kD = 512, kDH = 64;
constexpr float kScale = 0.125f;   // 1/sqrt(64)
constexpr float kNeg = -1e9f;

typedef __attribute__((ext_vector_type(8))) short bf16x8;
typedef __attribute__((ext_vector_type(4))) float f32x4;

__device__ __forceinline__ unsigned short f2bf(float f) {
  union { float f; unsigned int u; } a; a.f = f;
  return (unsigned short)((a.u + 0x7FFFu + ((a.u >> 16) & 1u)) >> 16);
}

// ---------------------------------------------------------------------------
// Kernel 1: C = relu(X @ W^T + bias), X:[8192,512] f32, W:[512,512] f32
// (W is already [n][k] row-major = B^T layout for MFMA).
// Output bf16 in head-split layout [b*H+h][s][64] into workspace.
// grid (4, 64, 3): x = n-tile, y = m-tile, z selects q/k/v.
// ---------------------------------------------------------------------------
__global__ __launch_bounds__(256)
void qkv_gemm_kernel(const float* __restrict__ xq, const float* __restrict__ xk,
                     const float* __restrict__ xv,
                     const float* __restrict__ wq, const float* __restrict__ wk,
                     const float* __restrict__ wv,
                     const float* __restrict__ bq, const float* __restrict__ bk,
                     const float* __restrict__ bv,
                     unsigned short* __restrict__ wsout)
{
  // 72 = 64 + 8 pad: 144 B rows, 16B-aligned, 2-way (free) bank conflict on
  // the 16-rows-at-same-offset ds_read_b128 fragment reads.
  __shared__ __align__(16) unsigned short As[128][72];
  __shared__ __align__(16) unsigned short Bs[128][72];

  const int z = blockIdx.z;
  const float* X    = (z == 0) ? xq : (z == 1) ? xk : xv;
  const float* W    = (z == 0) ? wq : (z == 1) ? wk : wv;
  const float* bias = (z == 0) ? bq : (z == 1) ? bk : bv;
  unsigned short* out = wsout + (size_t)z * (kB * kS * kD);

  const int m0 = blockIdx.y * 128;
  const int n0 = blockIdx.x * 128;
  const int t = threadIdx.x;
  const int lane = t & 63;
  const int w = t >> 6;
  const int wr = w >> 1, wc = w & 1;       // 2x2 wave grid, 64x64 out each
  const int l16 = lane & 15, lg = lane >> 4;

  f32x4 acc[4][4] = {};

  for (int kt = 0; kt < kD; kt += 64) {
    __syncthreads();
    // stage A-tile [128][64] and B-tile [128][64] (f32 -> bf16)
#pragma unroll
    for (int i = 0; i < 4; ++i) {
      const int c = t + 256 * i;           // 0..1023
      const int row = c >> 3, c8 = (c & 7) * 8;
      const float* srcA = X + (size_t)(m0 + row) * kD + kt + c8;
      float4 a0 = *(const float4*)srcA;
      float4 a1 = *(const float4*)(srcA + 4);
      uint4 ua;
      ua.x = f2bf(a0.x) | ((unsigned)f2bf(a0.y) << 16);
      ua.y = f2bf(a0.z) | ((unsigned)f2bf(a0.w) << 16);
      ua.z = f2bf(a1.x) | ((unsigned)f2bf(a1.y) << 16);
      ua.w = f2bf(a1.z) | ((unsigned)f2bf(a1.w) << 16);
      *(uint4*)&As[row][c8] = ua;

      const float* srcB = W + (size_t)(n0 + row) * kD + kt + c8;
      float4 b0 = *(const float4*)srcB;
      float4 b1 = *(const float4*)(srcB + 4);
      uint4 ub;
      ub.x = f2bf(b0.x) | ((unsigned)f2bf(b0.y) << 16);
      ub.y = f2bf(b0.z) | ((unsigned)f2bf(b0.w) << 16);
      ub.z = f2bf(b1.x) | ((unsigned)f2bf(b1.y) << 16);
      ub.w = f2bf(b1.z) | ((unsigned)f2bf(b1.w) << 16);
      *(uint4*)&Bs[row][c8] = ub;
    }
    __syncthreads();

#pragma unroll
    for (int kk = 0; kk < 2; ++kk) {
      bf16x8 av[4];
#pragma unroll
      for (int mf = 0; mf < 4; ++mf)
        av[mf] = *(const bf16x8*)&As[wr * 64 + mf * 16 + l16][kk * 32 + lg * 8];
#pragma unroll
      for (int nf = 0; nf < 4; ++nf) {
        bf16x8 bfr = *(const bf16x8*)&Bs[wc * 64 + nf * 16 + l16][kk * 32 + lg * 8];
#pragma unroll
        for (int mf = 0; mf < 4; ++mf)
          acc[mf][nf] = __builtin_amdgcn_mfma_f32_16x16x32_bf16(av[mf], bfr, acc[mf][nf], 0, 0, 0);
      }
    }
  }

  // epilogue: bias + relu -> bf16, head-split layout
#pragma unroll
  for (int nf = 0; nf < 4; ++nf) {
    const int n = n0 + wc * 64 + nf * 16 + l16;
    const float bval = bias[n];
    const int h = n >> 6, dd = n & 63;
#pragma unroll
    for (int mf = 0; mf < 4; ++mf) {
#pragma unroll
      for (int r = 0; r < 4; ++r) {
        const int m = m0 + wr * 64 + mf * 16 + lg * 4 + r;  // C row = (lane>>4)*4+reg
        const int b_ = m >> 10, s = m & 1023;
        float vv = acc[mf][nf][r] + bval;
        vv = vv > 0.f ? vv : 0.f;
        out[((size_t)(b_ * kH + h) * kS + s) * kDH + dd] = f2bf(vv);
      }
    }
  }
}

// ---------------------------------------------------------------------------
// Kernel 2: flash attention per (bh, 64-row q-tile). 4 waves, 16 q-rows each.
// KVBLK = 64. Online softmax, wave-parallel. Key mask row = (bh % kB)
// (reproduces the reference's head-major tile vs batch-major heads quirk).
// Writes y (pre-residual, pre-qmask) f32 into d_out, layout [b][s][512].
// ---------------------------------------------------------------------------
__global__ __launch_bounds__(256)
void attn_kernel(const unsigned short* __restrict__ ws,
                 const int* __restrict__ key_mask,
                 float* __restrict__ y)
{
  __shared__ __align__(16) unsigned short Qs[64][72];
  __shared__ __align__(16) unsigned short Ks[64][72];
  __shared__ __align__(16) unsigned short Vt[64][72];   // V transposed: [dd][k]
  __shared__ __align__(16) unsigned short Ps[4][16][72];
  __shared__ float kmadd[64];

  const unsigned short* Qw = ws;
  const unsigned short* Kw = ws + (size_t)1 * kB * kS * kD;
  const unsigned short* Vw = ws + (size_t)2 * kB * kS * kD;

  const int bh = blockIdx.y;
  const int q0 = blockIdx.x * 64;
  const int t = threadIdx.x;
  const int w = t >> 6, lane = t & 63;
  const int l16 = lane & 15, lg = lane >> 4;
  const int b_ = bh / kH, h = bh % kH;

  const unsigned short* Qb = Qw + ((size_t)bh * kS + q0) * kDH;
  const unsigned short* Kb = Kw + (size_t)bh * kS * kDH;
  const unsigned short* Vb = Vw + (size_t)bh * kS * kDH;
  const int* km = key_mask + (bh % kB) * kS;

  // stage Q tile [64][64]
#pragma unroll
  for (int i = 0; i < 2; ++i) {
    const int c = t + 256 * i;
    const int row = c >> 3, c8 = (c & 7) * 8;
    *(uint4*)&Qs[row][c8] = *(const uint4*)(Qb + (size_t)row * kDH + c8);
  }

  f32x4 o[4] = {};
  float m_[4], l_[4];
#pragma unroll
  for (int r = 0; r < 4; ++r) { m_[r] = -__builtin_inff(); l_[r] = 0.f; }

  for (int kv0 = 0; kv0 < kS; kv0 += 64) {
    __syncthreads();
    // stage K tile and V^T tile
#pragma unroll
    for (int i = 0; i < 2; ++i) {
      const int c = t + 256 * i;
      const int row = c >> 3, c8 = (c & 7) * 8;
      *(uint4*)&Ks[row][c8] = *(const uint4*)(Kb + (size_t)(kv0 + row) * kDH + c8);
      uint4 vv = *(const uint4*)(Vb + (size_t)(kv0 + row) * kDH + c8);
      unsigned int w4[4] = { vv.x, vv.y, vv.z, vv.w };
#pragma unroll
      for (int j2 = 0; j2 < 4; ++j2) {
        Vt[c8 + j2 * 2][row]     = (unsigned short)(w4[j2] & 0xffffu);
        Vt[c8 + j2 * 2 + 1][row] = (unsigned short)(w4[j2] >> 16);
      }
    }
    if (t < 64) kmadd[t] = km[kv0 + t] ? 0.f : kNeg;
    __syncthreads();

    // S = Q K^T  (wave's 16 q-rows x 64 keys)
    f32x4 sc[4] = {};
#pragma unroll
    for (int kk = 0; kk < 2; ++kk) {
      bf16x8 a = *(const bf16x8*)&Qs[w * 16 + l16][kk * 32 + lg * 8];
#pragma unroll
      for (int nf = 0; nf < 4; ++nf) {
        bf16x8 bfr = *(const bf16x8*)&Ks[nf * 16 + l16][kk * 32 + lg * 8];
        sc[nf] = __builtin_amdgcn_mfma_f32_16x16x32_bf16(a, bfr, sc[nf], 0, 0, 0);
      }
    }

    float madd[4];
#pragma unroll
    for (int nf = 0; nf < 4; ++nf) madd[nf] = kmadd[nf * 16 + l16];

    // online softmax per C-row r (row = lg*4 + r), cols spread over 16 lanes
#pragma unroll
    for (int r = 0; r < 4; ++r) {
      float s0 = sc[0][r] * kScale + madd[0];
      float s1 = sc[1][r] * kScale + madd[1];
      float s2 = sc[2][r] * kScale + madd[2];
      float s3 = sc[3][r] * kScale + madd[3];
      float mx = fmaxf(fmaxf(s0, s1), fmaxf(s2, s3));
      mx = fmaxf(mx, __shfl_xor(mx, 1));
      mx = fmaxf(mx, __shfl_xor(mx, 2));
      mx = fmaxf(mx, __shfl_xor(mx, 4));
      mx = fmaxf(mx, __shfl_xor(mx, 8));
      const float mnew = fmaxf(m_[r], mx);
      const float f = __expf(m_[r] - mnew);   // -inf -> 0 on first tile
      const float p0 = __expf(s0 - mnew);
      const float p1 = __expf(s1 - mnew);
      const float p2 = __expf(s2 - mnew);
      const float p3 = __expf(s3 - mnew);
      float ls = p0 + p1 + p2 + p3;
      ls += __shfl_xor(ls, 1);
      ls += __shfl_xor(ls, 2);
      ls += __shfl_xor(ls, 4);
      ls += __shfl_xor(ls, 8);
      l_[r] = l_[r] * f + ls;
      m_[r] = mnew;
#pragma unroll
      for (int nd = 0; nd < 4; ++nd) o[nd][r] *= f;
      const int prow = lg * 4 + r;
      Ps[w][prow][0 * 16 + l16] = f2bf(p0);
      Ps[w][prow][1 * 16 + l16] = f2bf(p1);
      Ps[w][prow][2 * 16 + l16] = f2bf(p2);
      Ps[w][prow][3 * 16 + l16] = f2bf(p3);
    }

    // O += P @ V   (P from per-wave LDS, V^T rows are contiguous in k)
#pragma unroll
    for (int kk = 0; kk < 2; ++kk) {
      bf16x8 a = *(const bf16x8*)&Ps[w][l16][kk * 32 + lg * 8];
#pragma unroll
      for (int nd = 0; nd < 4; ++nd) {
        bf16x8 bfr = *(const bf16x8*)&Vt[nd * 16 + l16][kk * 32 + lg * 8];
        o[nd] = __builtin_amdgcn_mfma_f32_16x16x32_bf16(a, bfr, o[nd], 0, 0, 0);
      }
    }
  }

  // epilogue: divide by l, write f32 y into [b][s][512] layout
  float rinv[4];
#pragma unroll
  for (int r = 0; r < 4; ++r) rinv[r] = 1.f / l_[r];
#pragma unroll
  for (int nd = 0; nd < 4; ++nd) {
#pragma unroll
    for (int r = 0; r < 4; ++r) {
      const int srow = q0 + w * 16 + lg * 4 + r;
      y[((size_t)b_ * kS + srow) * kD + h * kDH + nd * 16 + l16] = o[nd][r] * rinv[r];
    }
  }
}

// ---------------------------------------------------------------------------
// Kernel 3: out = LN(qmask*y + q) * gamma + beta, in-place on d_out.
// One wave per row; qmask row = ((b*H + h) % B)  (same reference quirk).
// ---------------------------------------------------------------------------
__global__ __launch_bounds__(256)
void ln_kernel(const float* __restrict__ y, const float* __restrict__ q,
               const int* __restrict__ qmask,
               const float* __restrict__ gamma, const float* __restrict__ beta,
               float* __restrict__ out)
{
  const int w = threadIdx.x >> 6, lane = threadIdx.x & 63;
  const int row = blockIdx.x * 4 + w;            // 0..8191
  const int b_ = row >> 10, s = row & 1023;
  const int d0 = lane * 8;
  const int h = d0 >> 6;

  const float* yp = y + (size_t)row * kD + d0;
  const float* qp = q + (size_t)row * kD + d0;
  const int qm = qmask[((b_ * kH + h) % kB) * kS + s];

  float4 y0 = *(const float4*)yp, y1 = *(const float4*)(yp + 4);
  float4 q0 = *(const float4*)qp, q1 = *(const float4*)(qp + 4);
  float vals[8] = { y0.x, y0.y, y0.z, y0.w, y1.x, y1.y, y1.z, y1.w };
  float qs[8]   = { q0.x, q0.y, q0.z, q0.w, q1.x, q1.y, q1.z, q1.w };

  float sum = 0.f, ss = 0.f;
#pragma unroll
  for (int j = 0; j < 8; ++j) {
    const float val = (qm ? vals[j] : 0.f) + qs[j];
    vals[j] = val; sum += val; ss += val * val;
  }
#pragma unroll
  for (int off = 1; off < 64; off <<= 1) {
    sum += __shfl_xor(sum, off);
    ss  += __shfl_xor(ss, off);
  }
  const float mu = sum * (1.f / kD);
  const float var = ss * (1.f / kD) - mu * mu;
  const float rstd = rsqrtf(var + 1e-6f);

  float4 g0 = *(const float4*)(gamma + d0), g1 = *(const float4*)(gamma + d0 + 4);
  float4 be0 = *(const float4*)(beta + d0), be1 = *(const float4*)(beta + d0 + 4);
  float gs[8] = { g0.x, g0.y, g0.z, g0.w, g1.x, g1.y, g1.z, g1.w };
  float bs[8] = { be0.x, be0.y, be0.z, be0.w, be1.x, be1.y, be1.z, be1.w };

  float4 o0, o1;
  o0.x = gs[0] * (vals[0] - mu) * rstd + bs[0];
  o0.y = gs[1] * (vals[1] - mu) * rstd + bs[1];
  o0.z = gs[2] * (vals[2] - mu) * rstd + bs[2];
  o0.w = gs[3] * (vals[3] - mu) * rstd + bs[3];
  o1.x = gs[4] * (vals[4] - mu) * rstd + bs[4];
  o1.y = gs[5] * (vals[5] - mu) * rstd + bs[5];
  o1.z = gs[6] * (vals[6] - mu) * rstd + bs[6];
  o1.w = gs[7] * (vals[7] - mu) * rstd + bs[7];
  *(float4*)(out + (size_t)row * kD + d0) = o0;
  *(float4*)(out + (size_t)row * kD + d0 + 4) = o1;
}

extern "C" void kernel_launch(void* const* d_in, const int* in_sizes, int n_in,
                              void* d_out, int out_size, void* d_ws, size_t ws_size,
                              hipStream_t stream) {
  const float* q  = (const float*)d_in[0];
  const float* k  = (const float*)d_in[1];
  const float* v  = (const float*)d_in[2];
  const int* qmask = (const int*)d_in[3];
  const int* kmask = (const int*)d_in[4];
  const float* Wq = (const float*)d_in[5];
  const float* bq = (const float*)d_in[6];
  const float* Wk = (const float*)d_in[7];
  const float* bk = (const float*)d_in[8];
  const float* Wv = (const float*)d_in[9];
  const float* bv = (const float*)d_in[10];
  const float* gamma = (const float*)d_in[11];
  const float* beta  = (const float*)d_in[12];
  float* out = (float*)d_out;
  unsigned short* wsqkv = (unsigned short*)d_ws;  // 3 x 8MB bf16 Q,K,V

  qkv_gemm_kernel<<<dim3(4, 64, 3), 256, 0, stream>>>(
      q, k, v, Wq, Wk, Wv, bq, bk, bv, wsqkv);
  attn_kernel<<<dim3(16, 64), 256, 0, stream>>>(wsqkv, kmask, out);
  ln_kernel<<<2048, 256, 0, stream>>>(out, q, qmask, gamma, beta, out);
}